// Round 3
// baseline (1081.492 us; speedup 1.0000x reference)
//
#include <hip/hip_runtime.h>

// Sinkhorn matching loss: B=16,T=64,N=256,D=128; 1024 frames.
// One block = one frame, 1024 threads = 16 waves.
// Phase 1: stage S,T as bf16 in LDS; cdist inner products via
//          mfma_f32_16x16x32_bf16. Wave w owns K rows [16w,16w+16) x all 256
//          cols as 16 f32x4 accumulator fragments (64 AGPRs).
// Phase 2: K = exp(-cost/tau) in-place in registers (cost recovered later as
//          -tau*log(K)).
// Phase 3: 10 Sinkhorn iterations. MFMA C/D layout (lane owns rows 16w+4q+r,
//          cols 16j+(lane&15)) makes the u-step a pure in-wave butterfly over
//          lane&15; v-step reduces over quads then one 16-wave LDS pass.
// Register budget: 64 acc (AGPR) + <64 arch VGPR = 128 -> 4 waves/EU.

typedef __bf16 bf16x8 __attribute__((ext_vector_type(8)));
typedef __bf16 bf16x4 __attribute__((ext_vector_type(4)));
typedef float floatx4 __attribute__((ext_vector_type(4)));

constexpr int N = 256;
constexpr int D = 128;
constexpr int NITER = 10;
#define TAUF 0.05f
#define EPSF 1e-8f
#define MUF  (1.0f / 256.0f)

constexpr int SRW = 136;              // bf16 row stride: 68 words -> 2-way (free) frag reads
constexpr int STAGE_B = N * SRW * 2;  // 69632 bytes per staged array

__global__ __launch_bounds__(1024) __attribute__((amdgpu_waves_per_eu(4, 4)))
void sinkhorn_kernel(const float* __restrict__ Sg, const float* __restrict__ Tg,
                     float* __restrict__ out)
{
    __shared__ __align__(16) char stage[2 * STAGE_B];  // Sb,Tb; red overlays Sb later
    __shared__ float s2[N], t2[N], vsh[N], wsum[16];

    __bf16 (*Sb)[SRW] = (__bf16(*)[SRW])stage;
    __bf16 (*Tb)[SRW] = (__bf16(*)[SRW])(stage + STAGE_B);
    float (*red)[N]   = (float(*)[N])stage;            // alive only after GEMM barrier

    const int tid  = threadIdx.x;
    const int lane = tid & 63;
    const int w    = tid >> 6;     // wave 0..15 -> K rows [16w, 16w+16)
    const int l15  = lane & 15;
    const int q    = lane >> 4;    // quad 0..3
    const int f    = blockIdx.x;

    // ---- Phase 1a: stage fp32 -> bf16 into LDS, fold in squared norms ----
    const int ln = tid >> 2;       // row 0..255
    const int lq = tid & 3;        // d-chunk of 32 floats
    const float4* Sv = (const float4*)(Sg + (size_t)f * N * D);
    const float4* Tv = (const float4*)(Tg + (size_t)f * N * D);

    float sqS = 0.f, sqT = 0.f;
#pragma unroll
    for (int t = 0; t < 8; ++t) {
        float4 a = Sv[ln * 32 + lq * 8 + t];
        float4 b = Tv[ln * 32 + lq * 8 + t];
        __bf16 a0 = (__bf16)a.x, a1 = (__bf16)a.y, a2 = (__bf16)a.z, a3 = (__bf16)a.w;
        __bf16 b0 = (__bf16)b.x, b1 = (__bf16)b.y, b2 = (__bf16)b.z, b3 = (__bf16)b.w;
        // norms from the ROUNDED values -> dsq is the exact distance of rounded pts
        float fa0 = (float)a0, fa1 = (float)a1, fa2 = (float)a2, fa3 = (float)a3;
        float fb0 = (float)b0, fb1 = (float)b1, fb2 = (float)b2, fb3 = (float)b3;
        sqS += fa0 * fa0 + fa1 * fa1 + fa2 * fa2 + fa3 * fa3;
        sqT += fb0 * fb0 + fb1 * fb1 + fb2 * fb2 + fb3 * fb3;
        bf16x4 pa = {a0, a1, a2, a3};
        bf16x4 pb = {b0, b1, b2, b3};
        *(bf16x4*)&Sb[ln][lq * 32 + t * 4] = pa;
        *(bf16x4*)&Tb[ln][lq * 32 + t * 4] = pb;
    }
    sqS += __shfl_xor(sqS, 1); sqS += __shfl_xor(sqS, 2);
    sqT += __shfl_xor(sqT, 1); sqT += __shfl_xor(sqT, 2);
    if (lq == 0) { s2[ln] = sqS; t2[ln] = sqT; }
    if (tid < N) vsh[tid] = 1.0f;
    __syncthreads();

    // ---- Phase 1b: MFMA GEMM. acc[j] = 16x16 tile (rows 16w.., cols 16j..) ----
    floatx4 acc[16];
#pragma unroll
    for (int j = 0; j < 16; ++j) acc[j] = (floatx4){0.f, 0.f, 0.f, 0.f};

#pragma unroll 1
    for (int kk = 0; kk < 4; ++kk) {
        bf16x8 afrag = *(const bf16x8*)&Sb[16 * w + l15][kk * 32 + q * 8];
#pragma unroll 4
        for (int j = 0; j < 16; ++j) {
            bf16x8 bfrag = *(const bf16x8*)&Tb[16 * j + l15][kk * 32 + q * 8];
            acc[j] = __builtin_amdgcn_mfma_f32_16x16x32_bf16(afrag, bfrag, acc[j], 0, 0, 0);
        }
    }

    // ---- Phase 2: K = exp(-cost/tau), in place ----
    // C/D layout: lane holds rows 16w + 4q + r (r=0..3), col 16j + l15.
    floatx4 s2r = *(const floatx4*)&s2[16 * w + 4 * q];
#pragma unroll
    for (int j = 0; j < 16; ++j) {
        float tc2 = t2[16 * j + l15];
#pragma unroll
        for (int r = 0; r < 4; ++r) {
            float dsq = s2r[r] + tc2 - 2.f * acc[j][r];
            float cst = sqrtf(fmaxf(dsq, 0.f));
            acc[j][r] = __expf(cst * (-1.f / TAUF));
        }
    }
    __syncthreads();   // all waves done reading Sb/Tb; red may now overlay

    // ---- Phase 3: Sinkhorn ----
    float u[4] = {0.f, 0.f, 0.f, 0.f};
#pragma unroll 1
    for (int it = 0; it < NITER; ++it) {
        // u-step: row sums of K*v ; reduction entirely in-wave (over l15)
        float rp[4] = {0.f, 0.f, 0.f, 0.f};
#pragma unroll
        for (int j = 0; j < 16; ++j) {
            float vv = vsh[16 * j + l15];
#pragma unroll
            for (int r = 0; r < 4; ++r) rp[r] = fmaf(acc[j][r], vv, rp[r]);
        }
#pragma unroll
        for (int m = 1; m <= 8; m <<= 1) {
#pragma unroll
            for (int r = 0; r < 4; ++r) rp[r] += __shfl_xor(rp[r], m);
        }
#pragma unroll
        for (int r = 0; r < 4; ++r) u[r] = MUF / (rp[r] + EPSF);

        // v-step: col sums of K^T*u ; reduce over quads, then across 16 waves
        float cp[16];
#pragma unroll
        for (int j = 0; j < 16; ++j) {
            float s = 0.f;
#pragma unroll
            for (int r = 0; r < 4; ++r) s = fmaf(acc[j][r], u[r], s);
            s += __shfl_xor(s, 16);
            s += __shfl_xor(s, 32);
            cp[j] = s;
        }
        if (q == 0) {
#pragma unroll
            for (int j = 0; j < 16; ++j) red[w][16 * j + l15] = cp[j];
        }
        __syncthreads();
        if (tid < N) {
            float s = 0.f;
#pragma unroll
            for (int ww = 0; ww < 16; ++ww) s += red[ww][tid];
            vsh[tid] = MUF / (s + EPSF);
        }
        __syncthreads();
    }

    // ---- final: sum u_n K_nm v_m cost_nm ; cost = -tau*log(K) ----
    float fsum = 0.f;
#pragma unroll
    for (int j = 0; j < 16; ++j) {
        float vv = vsh[16 * j + l15];
#pragma unroll
        for (int r = 0; r < 4; ++r) {
            float K = acc[j][r];
            float cst = -TAUF * __logf(K);
            fsum += u[r] * K * vv * cst;
        }
    }
#pragma unroll
    for (int m = 1; m <= 32; m <<= 1) fsum += __shfl_xor(fsum, m);
    if (lane == 0) wsum[w] = fsum;
    __syncthreads();
    if (tid == 0) {
        float s = 0.f;
#pragma unroll
        for (int ww = 0; ww < 16; ++ww) s += wsum[ww];
        atomicAdd(out, s * (1.0f / 1024.0f));
    }
}

extern "C" void kernel_launch(void* const* d_in, const int* in_sizes, int n_in,
                              void* d_out, int out_size, void* d_ws, size_t ws_size,
                              hipStream_t stream) {
    const float* S = (const float*)d_in[0];
    const float* T = (const float*)d_in[1];
    float* out = (float*)d_out;
    hipMemsetAsync(out, 0, sizeof(float), stream);
    sinkhorn_kernel<<<dim3(1024), dim3(1024), 0, stream>>>(S, T, out);
}

// Round 4
// 485.069 us; speedup vs baseline: 2.2296x; 2.2296x over previous
//
#include <hip/hip_runtime.h>

// Sinkhorn matching loss: B=16,T=64,N=256,D=128; 1024 frames.
// One block = one frame, 1024 threads = 16 waves.
// Phase 1: stage S,T as bf16 in LDS; cdist inner products via
//          mfma_f32_16x16x32_bf16. Wave w owns K rows [16w,16w+16) x all 256
//          cols as 16 f32x4 accumulator fragments (64 regs of unified file).
// Phase 2: K = exp(-cost/tau) in-place (cost recovered later as -tau*log K).
// Phase 3: 10 Sinkhorn iterations; u-step reduction is a pure in-wave
//          butterfly over l15, v-step reduces over quads then 16 waves in LDS.
//
// HARD RULE (round-3 lesson): every loop indexing acc[] must be FULLY
// unrolled. '#pragma unroll 4' left a runtime index -> acc demoted to
// scratch -> 3.6 GB of spill traffic, 925 us. Register budget: 64 acc +
// <64 arch = 128 (the cap for 1024-thread blocks).

typedef __bf16 bf16x8 __attribute__((ext_vector_type(8)));
typedef __bf16 bf16x4 __attribute__((ext_vector_type(4)));
typedef float floatx4 __attribute__((ext_vector_type(4)));

constexpr int N = 256;
constexpr int D = 128;
constexpr int NITER = 10;
#define TAUF 0.05f
#define EPSF 1e-8f
#define MUF  (1.0f / 256.0f)

constexpr int SRW = 136;              // bf16 row stride: 68 words -> rows step 4 banks -> 2-way (free)
constexpr int STAGE_B = N * SRW * 2;  // 69632 bytes per staged array

__global__ __launch_bounds__(1024) __attribute__((amdgpu_waves_per_eu(4, 4)))
void sinkhorn_kernel(const float* __restrict__ Sg, const float* __restrict__ Tg,
                     float* __restrict__ out)
{
    __shared__ __align__(16) char stage[2 * STAGE_B];  // Sb,Tb; red overlays Sb later
    __shared__ float s2[N], t2[N], vsh[N], wsum[16];

    __bf16 (*Sb)[SRW] = (__bf16(*)[SRW])stage;
    __bf16 (*Tb)[SRW] = (__bf16(*)[SRW])(stage + STAGE_B);
    float (*red)[N]   = (float(*)[N])stage;            // alive only after GEMM barrier

    const int tid  = threadIdx.x;
    const int lane = tid & 63;
    const int w    = tid >> 6;     // wave 0..15 -> K rows [16w, 16w+16)
    const int l15  = lane & 15;
    const int q    = lane >> 4;    // quad 0..3
    const int f    = blockIdx.x;

    // ---- Phase 1a: stage fp32 -> bf16 into LDS, fold in squared norms ----
    const int ln = tid >> 2;       // row 0..255
    const int lq = tid & 3;        // d-chunk of 32 floats
    const float4* Sv = (const float4*)(Sg + (size_t)f * N * D);
    const float4* Tv = (const float4*)(Tg + (size_t)f * N * D);

    float sqS = 0.f, sqT = 0.f;
#pragma unroll 2
    for (int t = 0; t < 8; ++t) {
        float4 a = Sv[ln * 32 + lq * 8 + t];
        float4 b = Tv[ln * 32 + lq * 8 + t];
        __bf16 a0 = (__bf16)a.x, a1 = (__bf16)a.y, a2 = (__bf16)a.z, a3 = (__bf16)a.w;
        __bf16 b0 = (__bf16)b.x, b1 = (__bf16)b.y, b2 = (__bf16)b.z, b3 = (__bf16)b.w;
        // norms from the ROUNDED values -> dsq is the exact distance of rounded pts
        float fa0 = (float)a0, fa1 = (float)a1, fa2 = (float)a2, fa3 = (float)a3;
        float fb0 = (float)b0, fb1 = (float)b1, fb2 = (float)b2, fb3 = (float)b3;
        sqS += fa0 * fa0 + fa1 * fa1 + fa2 * fa2 + fa3 * fa3;
        sqT += fb0 * fb0 + fb1 * fb1 + fb2 * fb2 + fb3 * fb3;
        bf16x4 pa = {a0, a1, a2, a3};
        bf16x4 pb = {b0, b1, b2, b3};
        *(bf16x4*)&Sb[ln][lq * 32 + t * 4] = pa;
        *(bf16x4*)&Tb[ln][lq * 32 + t * 4] = pb;
    }
    sqS += __shfl_xor(sqS, 1); sqS += __shfl_xor(sqS, 2);
    sqT += __shfl_xor(sqT, 1); sqT += __shfl_xor(sqT, 2);
    if (lq == 0) { s2[ln] = sqS; t2[ln] = sqT; }
    if (tid < N) vsh[tid] = 1.0f;
    __syncthreads();

    // ---- Phase 1b: MFMA GEMM. acc[j] = 16x16 tile (rows 16w.., cols 16j..) ----
    floatx4 acc[16];
#pragma unroll
    for (int j = 0; j < 16; ++j) acc[j] = (floatx4){0.f, 0.f, 0.f, 0.f};

#pragma unroll 1
    for (int kk = 0; kk < 4; ++kk) {
        bf16x8 afrag = *(const bf16x8*)&Sb[16 * w + l15][kk * 32 + q * 8];
#pragma unroll
        for (int j = 0; j < 16; ++j) {   // FULL unroll: acc[j] must stay static
            bf16x8 bfrag = *(const bf16x8*)&Tb[16 * j + l15][kk * 32 + q * 8];
            acc[j] = __builtin_amdgcn_mfma_f32_16x16x32_bf16(afrag, bfrag, acc[j], 0, 0, 0);
        }
    }

    // ---- Phase 2: K = exp(-cost/tau), in place ----
    // C/D layout: lane holds rows 16w + 4q + r (r=0..3), col 16j + l15.
    floatx4 s2r = *(const floatx4*)&s2[16 * w + 4 * q];
#pragma unroll
    for (int j = 0; j < 16; ++j) {
        float tc2 = t2[16 * j + l15];
#pragma unroll
        for (int r = 0; r < 4; ++r) {
            float dsq = s2r[r] + tc2 - 2.f * acc[j][r];
            float cst = sqrtf(fmaxf(dsq, 0.f));
            acc[j][r] = __expf(cst * (-1.f / TAUF));
        }
    }
    __syncthreads();   // all waves done reading Sb/Tb; red may now overlay

    // ---- Phase 3: Sinkhorn ----
    float u[4] = {0.f, 0.f, 0.f, 0.f};
#pragma unroll 1
    for (int it = 0; it < NITER; ++it) {
        // u-step: row sums of K*v ; reduction entirely in-wave (over l15)
        float rp[4] = {0.f, 0.f, 0.f, 0.f};
#pragma unroll
        for (int j = 0; j < 16; ++j) {
            float vv = vsh[16 * j + l15];
#pragma unroll
            for (int r = 0; r < 4; ++r) rp[r] = fmaf(acc[j][r], vv, rp[r]);
        }
#pragma unroll
        for (int m = 1; m <= 8; m <<= 1) {
#pragma unroll
            for (int r = 0; r < 4; ++r) rp[r] += __shfl_xor(rp[r], m);
        }
#pragma unroll
        for (int r = 0; r < 4; ++r) u[r] = MUF / (rp[r] + EPSF);

        // v-step: col sums of K^T*u ; reduce over quads, then across 16 waves
#pragma unroll
        for (int j = 0; j < 16; ++j) {
            float s = 0.f;
#pragma unroll
            for (int r = 0; r < 4; ++r) s = fmaf(acc[j][r], u[r], s);
            s += __shfl_xor(s, 16);
            s += __shfl_xor(s, 32);
            if (q == 0) red[w][16 * j + l15] = s;   // predicated, no cp[16] array
        }
        __syncthreads();
        if (tid < N) {
            float s = 0.f;
#pragma unroll
            for (int ww = 0; ww < 16; ++ww) s += red[ww][tid];
            vsh[tid] = MUF / (s + EPSF);
        }
        __syncthreads();
    }

    // ---- final: sum u_n K_nm v_m cost_nm ; cost = -tau*log(K) ----
    float fsum = 0.f;
#pragma unroll
    for (int j = 0; j < 16; ++j) {
        float vv = vsh[16 * j + l15];
#pragma unroll
        for (int r = 0; r < 4; ++r) {
            float K = acc[j][r];
            float cst = -TAUF * __logf(K);
            fsum += u[r] * K * vv * cst;
        }
    }
#pragma unroll
    for (int m = 1; m <= 32; m <<= 1) fsum += __shfl_xor(fsum, m);
    if (lane == 0) wsum[w] = fsum;
    __syncthreads();
    if (tid == 0) {
        float s = 0.f;
#pragma unroll
        for (int ww = 0; ww < 16; ++ww) s += wsum[ww];
        atomicAdd(out, s * (1.0f / 1024.0f));
    }
}

extern "C" void kernel_launch(void* const* d_in, const int* in_sizes, int n_in,
                              void* d_out, int out_size, void* d_ws, size_t ws_size,
                              hipStream_t stream) {
    const float* S = (const float*)d_in[0];
    const float* T = (const float*)d_in[1];
    float* out = (float*)d_out;
    hipMemsetAsync(out, 0, sizeof(float), stream);
    sinkhorn_kernel<<<dim3(1024), dim3(1024), 0, stream>>>(S, T, out);
}